// Round 8
// baseline (694.478 us; speedup 1.0000x reference)
//
#include <hip/hip_runtime.h>
#include <hip/hip_bf16.h>

#define NODES 100000
#define EDGES 1600000
#define NGRAPH 512
#define NTILES 98  // ceil(100001 / 1024)

using bf16 = __hip_bfloat16;
typedef long long ll;

__device__ __forceinline__ float lrelu(float v) { return v > 0.0f ? v : 0.2f * v; }

__device__ __forceinline__ unsigned mapf(float f) {
    unsigned u = __float_as_uint(f);
    return (u & 0x80000000u) ? ~u : (u | 0x80000000u);
}
__device__ __forceinline__ float unmapf(unsigned u) {
    return __uint_as_float((u & 0x80000000u) ? (u ^ 0x80000000u) : ~u);
}

__device__ __forceinline__ int idx_at(const void* raw, int i, int f) {
    return f ? (int)((const ll*)raw)[i] : ((const int*)raw)[i];
}

__global__ void detect_int64(const int* __restrict__ w, int* __restrict__ flag) {
    __shared__ int red[4];
    int t = threadIdx.x;
    int v = 0;
    for (int i = t; i < 4096; i += 256) v |= w[2 * i + 1];
    for (int o = 32; o; o >>= 1) v |= __shfl_xor(v, o);
    if ((t & 63) == 0) red[t >> 6] = v;
    __syncthreads();
    if (t == 0) flag[0] = ((red[0] | red[1] | red[2] | red[3]) == 0) ? 1 : 0;
}

__global__ void sentinel_kernel(float* out, float v) {
    int i = blockIdx.x * blockDim.x + threadIdx.x;
    if (i < NGRAPH * 10) out[i] = v;
}

// fused init: deg=0, pooled=sentinel
__global__ void init_kernel(int* __restrict__ deg, unsigned* __restrict__ pooled) {
    int i = blockIdx.x * blockDim.x + threadIdx.x;
    if (i < NODES) deg[i] = 0;
    if (i < NGRAPH * 64) pooled[i] = mapf(-1e4f);
}

// degree over dst; require BOTH endpoints valid so fill_csr fills every slot
__global__ void degree_kernel(const void* __restrict__ ei, const int* __restrict__ flag,
                              int* __restrict__ deg) {
    int i = blockIdx.x * blockDim.x + threadIdx.x;
    if (i >= EDGES) return;
    int f = flag[0];
    int s = idx_at(ei, i, f), d = idx_at(ei, EDGES + i, f);
    if ((unsigned)s < NODES && (unsigned)d < NODES) atomicAdd(&deg[d], 1);
}

// fused: dinv1/dinv2 + xs = bf16(x * dinv1); one wave per row
__global__ void dinv_prescale(const int* __restrict__ deg, const float* __restrict__ x,
                              float* __restrict__ dinv1, float* __restrict__ dinv2,
                              bf16* __restrict__ xs) {
    int wave = threadIdx.x >> 6, lane = threadIdx.x & 63;
    int row = blockIdx.x * 4 + wave;
    if (row >= NODES) return;
    float cdeg = (float)deg[row];
    float d1 = 1.0f / sqrtf(cdeg + 2.0f);
    float d2 = 1.0f / sqrtf(cdeg + 1.0f);
    if (lane == 0) { dinv1[row] = d1; dinv2[row] = d2; }
    xs[(size_t)row * 64 + lane] = __float2bfloat16(x[(size_t)row * 64 + lane] * d1);
}

// ---- exclusive scan of deg -> row_ptr (+ cursor copy) ----
__global__ void scanA(const int* __restrict__ deg, int* __restrict__ blocksum) {
    __shared__ int red[4];
    int b = blockIdx.x, t = threadIdx.x;
    int base = b * 1024;
    int s = 0;
#pragma unroll
    for (int k = 0; k < 4; ++k) {
        int i = base + t + k * 256;
        if (i < NODES) s += deg[i];
    }
    for (int o = 32; o; o >>= 1) s += __shfl_xor(s, o);
    if ((t & 63) == 0) red[t >> 6] = s;
    __syncthreads();
    if (t == 0) blocksum[b] = red[0] + red[1] + red[2] + red[3];
}

__global__ void scanB(const int* __restrict__ blocksum, int* __restrict__ blockoff) {
    __shared__ int sc[128];
    int t = threadIdx.x;
    int v = (t < NTILES) ? blocksum[t] : 0;
    sc[t] = v;
    __syncthreads();
    for (int o = 1; o < 128; o <<= 1) {
        int u = (t >= o) ? sc[t - o] : 0;
        __syncthreads();
        sc[t] += u;
        __syncthreads();
    }
    if (t < NTILES) blockoff[t] = sc[t] - v;  // exclusive
}

__global__ void scanC(const int* __restrict__ deg, const int* __restrict__ blockoff,
                      int* __restrict__ row_ptr, int* __restrict__ cursor) {
    __shared__ int sc[256];
    int b = blockIdx.x, t = threadIdx.x;
    int base = b * 1024 + t * 4;
    int v[4];
#pragma unroll
    for (int k = 0; k < 4; ++k) {
        int i = base + k;
        v[k] = (i < NODES) ? deg[i] : 0;
    }
    int tsum = v[0] + v[1] + v[2] + v[3];
    sc[t] = tsum;
    __syncthreads();
    for (int o = 1; o < 256; o <<= 1) {
        int u = (t >= o) ? sc[t - o] : 0;
        __syncthreads();
        sc[t] += u;
        __syncthreads();
    }
    int excl = sc[t] - tsum + blockoff[b];
#pragma unroll
    for (int k = 0; k < 4; ++k) {
        int i = base + k;
        if (i <= NODES) row_ptr[i] = excl;
        if (i < NODES) cursor[i] = excl;
        excl += v[k];
    }
}
// ----------------------------------------------------------

__global__ void fill_csr(const void* __restrict__ ei, const int* __restrict__ flag,
                         int* __restrict__ cursor, int* __restrict__ csr_src) {
    int i = blockIdx.x * blockDim.x + threadIdx.x;
    if (i >= EDGES) return;
    int f = flag[0];
    int s = idx_at(ei, i, f), d = idx_at(ei, EDGES + i, f);
    if ((unsigned)s >= NODES || (unsigned)d >= NODES) return;
    int slot = atomicAdd(&cursor[d], 1);  // cursor pre-seeded with row_ptr
    csr_src[slot] = s;
}

// paired gather: lane covers column pair c=lane&31; half-wave h=lane>>5 covers
// alternating edges. One dword load = 2 full source rows per wave-instruction.
// Returns (sum_{src} feat[src][2c], sum feat[src][2c+1]) replicated across halves.
__device__ __forceinline__ void gather_pairs(const unsigned* __restrict__ feat2,
                                             const int* __restrict__ csr, int beg, int end,
                                             int lane, float& outx, float& outy) {
    int h = lane >> 5, c = lane & 31;
    float ax = 0, ay = 0, bx = 0, by = 0, cx = 0, cy = 0, dx = 0, dy = 0;
    for (int cb = beg; cb < end; cb += 64) {
        int cnt = min(64, end - cb);
        int idx = (cb + lane < end) ? csr[cb + lane] : 0;
        int cnt2 = cnt & ~1;
        int j = 0;
        for (; j + 7 < cnt2; j += 8) {
            int s0 = __shfl(idx, j + h);
            int s1 = __shfl(idx, j + 2 + h);
            int s2 = __shfl(idx, j + 4 + h);
            int s3 = __shfl(idx, j + 6 + h);
            unsigned u0 = feat2[(size_t)s0 * 32 + c];
            unsigned u1 = feat2[(size_t)s1 * 32 + c];
            unsigned u2 = feat2[(size_t)s2 * 32 + c];
            unsigned u3 = feat2[(size_t)s3 * 32 + c];
            ax += __uint_as_float(u0 << 16);
            ay += __uint_as_float(u0 & 0xffff0000u);
            bx += __uint_as_float(u1 << 16);
            by += __uint_as_float(u1 & 0xffff0000u);
            cx += __uint_as_float(u2 << 16);
            cy += __uint_as_float(u2 & 0xffff0000u);
            dx += __uint_as_float(u3 << 16);
            dy += __uint_as_float(u3 & 0xffff0000u);
        }
        for (; j < cnt2; j += 2) {
            int s0 = __shfl(idx, j + h);
            unsigned u0 = feat2[(size_t)s0 * 32 + c];
            ax += __uint_as_float(u0 << 16);
            ay += __uint_as_float(u0 & 0xffff0000u);
        }
        if (cnt & 1) {  // odd tail: half 0 only
            int s0 = __shfl(idx, cnt - 1);
            if (h == 0) {
                unsigned u0 = feat2[(size_t)s0 * 32 + c];
                ax += __uint_as_float(u0 << 16);
                ay += __uint_as_float(u0 & 0xffff0000u);
            }
        }
    }
    float sx = (ax + bx) + (cx + dx);
    float sy = (ay + by) + (cy + dy);
    sx += __shfl_xor(sx, 32);
    sy += __shfl_xor(sy, 32);
    outx = sx;
    outy = sy;
}

// fused layer1: gather(xs) + self-loop + @W1 + b1 + LN + leaky -> h1s = h1*dinv2 (bf16)
__global__ void gcn1_fused(const unsigned* __restrict__ xs2, const int* __restrict__ csr,
                           const int* __restrict__ rp, const float* __restrict__ dinv1,
                           const float* __restrict__ dinv2, const float* __restrict__ W1,
                           const float* __restrict__ b1, const float* __restrict__ lng,
                           const float* __restrict__ lnb, bf16* __restrict__ h1s) {
    __shared__ float Wl[4096];
    int t = threadIdx.x;
    for (int i = t; i < 4096; i += 256) Wl[i] = W1[i];
    __syncthreads();
    int lane = t & 63, wave = t >> 6;
    int row = blockIdx.x * 4 + wave;
    if (row >= NODES) return;
    int c = lane & 31;
    float sx, sy;
    gather_pairs(xs2, csr, rp[row], rp[row + 1], lane, sx, sy);
    unsigned us = xs2[(size_t)row * 32 + c];
    float dv = dinv1[row];
    float vx = dv * (sx + 2.0f * __uint_as_float(us << 16));
    float vy = dv * (sy + 2.0f * __uint_as_float(us & 0xffff0000u));
    float a = b1[lane];
#pragma unroll
    for (int cc = 0; cc < 32; ++cc) {
        float wx = __shfl(vx, cc);
        float wy = __shfl(vy, cc);
        a += wx * Wl[(2 * cc) * 64 + lane] + wy * Wl[(2 * cc + 1) * 64 + lane];
    }
    float s = a;
    for (int o = 32; o; o >>= 1) s += __shfl_xor(s, o);
    float mu = s * (1.0f / 64.0f);
    float d = a - mu;
    float q = d * d;
    for (int o = 32; o; o >>= 1) q += __shfl_xor(q, o);
    float var = q * (1.0f / 64.0f);
    float y = d / sqrtf(var + 1e-5f) * lng[lane] + lnb[lane];
    h1s[(size_t)row * 64 + lane] = __float2bfloat16(lrelu(y) * dinv2[row]);
}

// fused layer2: gather(h1s) + self-loop + @W2 + b2 + leaky + max-pool
__global__ void gcn2_fused(const unsigned* __restrict__ h1s2, const int* __restrict__ csr,
                           const int* __restrict__ rp, const float* __restrict__ dinv2,
                           const float* __restrict__ W2, const float* __restrict__ b2,
                           const void* __restrict__ batch, const int* __restrict__ flag,
                           unsigned* __restrict__ pooled) {
    __shared__ float Wl[4096];
    int t = threadIdx.x;
    for (int i = t; i < 4096; i += 256) Wl[i] = W2[i];
    __syncthreads();
    int lane = t & 63, wave = t >> 6;
    int row = blockIdx.x * 4 + wave;
    if (row >= NODES) return;
    int c = lane & 31;
    float sx, sy;
    gather_pairs(h1s2, csr, rp[row], rp[row + 1], lane, sx, sy);
    unsigned us = h1s2[(size_t)row * 32 + c];
    float dv = dinv2[row];
    float vx = dv * (sx + __uint_as_float(us << 16));
    float vy = dv * (sy + __uint_as_float(us & 0xffff0000u));
    float a = b2[lane];
#pragma unroll
    for (int cc = 0; cc < 32; ++cc) {
        float wx = __shfl(vx, cc);
        float wy = __shfl(vy, cc);
        a += wx * Wl[(2 * cc) * 64 + lane] + wy * Wl[(2 * cc + 1) * 64 + lane];
    }
    a = lrelu(a);
    int g = idx_at(batch, row, flag[0]);
    if ((unsigned)g < NGRAPH) atomicMax(&pooled[g * 64 + lane], mapf(a));
}

// head: z = pooled@W3+b3; LN; leaky; z@W4+b4; softmax. One block per graph.
__global__ void head_kernel(const unsigned* __restrict__ pooled, const float* __restrict__ W3,
                            const float* __restrict__ b3, const float* __restrict__ g2,
                            const float* __restrict__ be2, const float* __restrict__ W4,
                            const float* __restrict__ b4, float* __restrict__ out) {
    __shared__ float prow[64];
    __shared__ float z[768];
    __shared__ float rs[4], rss[4];
    __shared__ float mu_s, rstd_s;
    __shared__ float red[10];
    int t = threadIdx.x, gI = blockIdx.x;
    if (t < 64) prow[t] = unmapf(pooled[gI * 64 + t]);
    __syncthreads();
    for (int c = t; c < 768; c += 256) {
        float acc = b3[c];
#pragma unroll 16
        for (int k = 0; k < 64; ++k) acc += prow[k] * W3[k * 768 + c];
        z[c] = acc;
    }
    __syncthreads();
    float s = 0.0f, ss = 0.0f;
    for (int c = t; c < 768; c += 256) {
        float v = z[c];
        s += v;
        ss += v * v;
    }
    for (int o = 32; o; o >>= 1) {
        s += __shfl_xor(s, o);
        ss += __shfl_xor(ss, o);
    }
    if ((t & 63) == 0) { rs[t >> 6] = s; rss[t >> 6] = ss; }
    __syncthreads();
    if (t == 0) {
        float S = rs[0] + rs[1] + rs[2] + rs[3];
        float SS = rss[0] + rss[1] + rss[2] + rss[3];
        float mu = S * (1.0f / 768.0f);
        float var = SS * (1.0f / 768.0f) - mu * mu;
        mu_s = mu;
        rstd_s = 1.0f / sqrtf(fmaxf(var, 0.0f) + 1e-5f);
    }
    __syncthreads();
    for (int c = t; c < 768; c += 256) {
        float y = (z[c] - mu_s) * rstd_s * g2[c] + be2[c];
        z[c] = lrelu(y);
    }
    if (t < 10) red[t] = 0.0f;
    __syncthreads();
    float p[10];
#pragma unroll
    for (int c = 0; c < 10; ++c) p[c] = 0.0f;
    for (int k = t; k < 768; k += 256) {
        float zv = z[k];
#pragma unroll
        for (int c = 0; c < 10; ++c) p[c] += zv * W4[k * 10 + c];
    }
#pragma unroll
    for (int c = 0; c < 10; ++c) atomicAdd(&red[c], p[c]);
    __syncthreads();
    if (t == 0) {
        float l[10], m = -1e30f;
#pragma unroll
        for (int c = 0; c < 10; ++c) {
            l[c] = red[c] + b4[c];
            m = fmaxf(m, l[c]);
        }
        float sum = 0.0f;
#pragma unroll
        for (int c = 0; c < 10; ++c) {
            l[c] = expf(l[c] - m);
            sum += l[c];
        }
        float inv = 1.0f / sum;
#pragma unroll
        for (int c = 0; c < 10; ++c) out[gI * 10 + c] = l[c] * inv;
    }
}

extern "C" void kernel_launch(void* const* d_in, const int* in_sizes, int n_in,
                              void* d_out, int out_size, void* d_ws, size_t ws_size,
                              hipStream_t stream) {
    const size_t REQUIRED = (size_t)NODES * 64 * 2 * 2  // xs + h1s (bf16)
                          + (size_t)EDGES * 4           // csr_src
                          + (size_t)(NODES + 1) * 4     // row_ptr
                          + (size_t)NODES * 4 * 4       // cursor, deg, dinv1, dinv2
                          + (size_t)NTILES * 4 * 2      // blocksum, blockoff
                          + (size_t)NGRAPH * 64 * 4     // pooled
                          + 16;                         // flag
    if (ws_size < REQUIRED) {
        sentinel_kernel<<<20, 256, 0, stream>>>((float*)d_out, 64.0f);
        return;
    }

    const float* x = (const float*)d_in[0];
    const void* ei = d_in[1];
    const void* batch = d_in[2];
    const float* W1 = (const float*)d_in[3];
    const float* b1 = (const float*)d_in[4];
    const float* lng = (const float*)d_in[5];
    const float* lnb = (const float*)d_in[6];
    const float* W2 = (const float*)d_in[7];
    const float* b2 = (const float*)d_in[8];
    const float* W3 = (const float*)d_in[9];
    const float* b3 = (const float*)d_in[10];
    const float* g2 = (const float*)d_in[11];
    const float* be2 = (const float*)d_in[12];
    const float* W4 = (const float*)d_in[13];
    const float* b4 = (const float*)d_in[14];

    bf16* xs = (bf16*)d_ws;                               // N*64 bf16
    bf16* h1s = xs + (size_t)NODES * 64;                  // N*64 bf16
    int* csr_src = (int*)(h1s + (size_t)NODES * 64);      // E
    int* row_ptr = csr_src + EDGES;                       // N+1
    int* cursor = row_ptr + (NODES + 1);                  // N
    int* deg = cursor + NODES;                            // N
    float* dinv1 = (float*)(deg + NODES);                 // N
    float* dinv2 = dinv1 + NODES;                         // N
    int* blocksum = (int*)(dinv2 + NODES);                // NTILES
    int* blockoff = blocksum + NTILES;                    // NTILES
    unsigned* pooled = (unsigned*)(blockoff + NTILES);    // G*64
    int* flag = (int*)(pooled + NGRAPH * 64);             // 1

    detect_int64<<<1, 256, 0, stream>>>((const int*)ei, flag);
    init_kernel<<<(NODES + 255) / 256, 256, 0, stream>>>(deg, pooled);

    // CSR build
    degree_kernel<<<(EDGES + 255) / 256, 256, 0, stream>>>(ei, flag, deg);
    dinv_prescale<<<(NODES + 3) / 4, 256, 0, stream>>>(deg, x, dinv1, dinv2, xs);
    scanA<<<NTILES, 256, 0, stream>>>(deg, blocksum);
    scanB<<<1, 128, 0, stream>>>(blocksum, blockoff);
    scanC<<<NTILES, 256, 0, stream>>>(deg, blockoff, row_ptr, cursor);
    fill_csr<<<(EDGES + 255) / 256, 256, 0, stream>>>(ei, flag, cursor, csr_src);

    // fused layers (one wave per destination row)
    gcn1_fused<<<(NODES + 3) / 4, 256, 0, stream>>>((const unsigned*)xs, csr_src, row_ptr,
                                                    dinv1, dinv2, W1, b1, lng, lnb, h1s);
    gcn2_fused<<<(NODES + 3) / 4, 256, 0, stream>>>((const unsigned*)h1s, csr_src, row_ptr,
                                                    dinv2, W2, b2, batch, flag, pooled);

    // head
    head_kernel<<<NGRAPH, 256, 0, stream>>>(pooled, W3, b3, g2, be2, W4, b4, (float*)d_out);
}